// Round 3
// baseline (1026.947 us; speedup 1.0000x reference)
//
#include <hip/hip_runtime.h>
#include <hip/hip_bf16.h>
#include <stdint.h>

typedef __bf16 bf16;
typedef __bf16 bf16x8 __attribute__((ext_vector_type(8)));
typedef float f32x4 __attribute__((ext_vector_type(4)));
typedef uint32_t u32x4 __attribute__((ext_vector_type(4)));

#define HD 128
#define LDP (HD + 8)
#define NTPB 4
#define MFMA __builtin_amdgcn_mfma_f32_16x16x32_bf16

__device__ inline float bflo(uint32_t u){ return __uint_as_float(u << 16); }
__device__ inline float bfhi(uint32_t u){ return __uint_as_float(u & 0xffff0000u); }
__device__ inline uint32_t packbf(float a, float b){
    bf16 x = (bf16)a, y = (bf16)b;
    uint16_t ux = __builtin_bit_cast(uint16_t, x), uy = __builtin_bit_cast(uint16_t, y);
    return (uint32_t)ux | ((uint32_t)uy << 16);
}
__device__ inline bf16x8 ldb8(const bf16* p){ return *(const bf16x8*)p; }
__device__ inline float sigm(float x){ return 1.f / (1.f + __expf(-x)); }
__device__ inline float tanh_fast(float x){ float t = __expf(-2.f * x); return (1.f - t) / (1.f + t); }

// ---------------- weight / activation conversion ----------------
__global__ void k_cvt(const float* __restrict__ in, bf16* __restrict__ out, int n){
    int i = blockIdx.x * 256 + threadIdx.x;
    if (i < n) out[i] = (bf16)in[i];
}

// ---------------- CSR (only the unsorted half needs building) ----------------
__global__ void k_bound(const int* __restrict__ dstB, int E, int* __restrict__ rows2, int n){
    int v = blockIdx.x * 256 + threadIdx.x;
    if (v > n) return;
    int lo = 0, hi = E;
    while (lo < hi){ int mid = (lo + hi) >> 1; if (dstB[mid] < v) lo = mid + 1; else hi = mid; }
    rows2[v] = lo;
}

__global__ void k_count(const int* __restrict__ dst, int* __restrict__ deg, int ne){
    int i = blockIdx.x * 256 + threadIdx.x;
    if (i < ne) atomicAdd(&deg[dst[i]], 1);
}

__global__ void k_scan1(const int* __restrict__ deg, int* __restrict__ rows,
                        int* __restrict__ bsum, int n){
    __shared__ int lds[256];
    int b = blockIdx.x, tid = threadIdx.x;
    int i0 = b * 1024 + tid * 4;
    int v[4]; int s = 0;
#pragma unroll
    for (int j = 0; j < 4; ++j){ int idx = i0 + j; v[j] = (idx < n) ? deg[idx] : 0; s += v[j]; }
    lds[tid] = s; __syncthreads();
    int acc = s;
    for (int off = 1; off < 256; off <<= 1){
        int add = (tid >= off) ? lds[tid - off] : 0;
        __syncthreads();
        acc += add; lds[tid] = acc;
        __syncthreads();
    }
    int run = acc - s;
#pragma unroll
    for (int j = 0; j < 4; ++j){ int idx = i0 + j; if (idx < n) rows[idx] = run; run += v[j]; }
    if (tid == 255) bsum[b] = acc;
}

__global__ void k_scan2(int* __restrict__ bsum, int nb){
    __shared__ int lds[128];
    int tid = threadIdx.x;
    int v = (tid < nb) ? bsum[tid] : 0;
    lds[tid] = v; __syncthreads();
    int acc = v;
    for (int off = 1; off < 128; off <<= 1){
        int add = (tid >= off) ? lds[tid - off] : 0;
        __syncthreads();
        acc += add; lds[tid] = acc;
        __syncthreads();
    }
    if (tid < nb) bsum[tid] = acc - v;
}

__global__ void k_scan3(int* __restrict__ rows, const int* __restrict__ bsum, int n, int total){
    int i = blockIdx.x * 256 + threadIdx.x;
    if (i < n) rows[i] += bsum[i >> 10];
    if (i == n) rows[n] = total;
}

__global__ void k_fill(const int* __restrict__ src, const int* __restrict__ dst,
                       int* __restrict__ cur, int* __restrict__ col, int ne){
    int i = blockIdx.x * 256 + threadIdx.x;
    if (i < ne){ int p = atomicAdd(&cur[dst[i]], 1); col[p] = src[i]; }
}

// ---------------- mean aggregation ----------------
__global__ __launch_bounds__(256) void k_gather(
    const bf16* __restrict__ curx,
    const int* __restrict__ srcB, const int* __restrict__ rows2,
    const int* __restrict__ colB, const int* __restrict__ rowsB,
    bf16* __restrict__ cout, int n)
{
    int wid = threadIdx.x >> 6, lane = threadIdx.x & 63;
    int v = blockIdx.x * 4 + wid;
    if (v >= n) return;
    int grp = lane >> 4, sl = lane & 15;
    int a0 = rows2[v], a1 = rows2[v + 1];
    int b0 = rowsB[v], b1 = rowsB[v + 1];
    int deg = (a1 - a0) + (b1 - b0);
    float inv = (deg > 0) ? 1.f / (float)deg : 0.f;

    const u32x4* base = (const u32x4*)curx;
    float acc[8];
#pragma unroll
    for (int k = 0; k < 8; ++k) acc[k] = 0.f;

    for (int j = a0 + grp; j < a1; j += 4){
        int nb = srcB[j];
        u32x4 q = base[(size_t)nb * 16 + sl];
#pragma unroll
        for (int k = 0; k < 4; ++k){ acc[2*k] += bflo(q[k]); acc[2*k+1] += bfhi(q[k]); }
    }
    for (int j = b0 + grp; j < b1; j += 4){
        int nb = colB[j];
        u32x4 q = base[(size_t)nb * 16 + sl];
#pragma unroll
        for (int k = 0; k < 4; ++k){ acc[2*k] += bflo(q[k]); acc[2*k+1] += bfhi(q[k]); }
    }
#pragma unroll
    for (int k = 0; k < 8; ++k){
        acc[k] += __shfl_xor(acc[k], 16);
        acc[k] += __shfl_xor(acc[k], 32);
    }
    if (grp == 0){
        u32x4 xv = base[(size_t)v * 16 + sl];
        u32x4 o;
#pragma unroll
        for (int k = 0; k < 4; ++k){
            float lo = bflo(xv[k]) + acc[2*k] * inv;
            float hi = bfhi(xv[k]) + acc[2*k+1] * inv;
            o[k] = packbf(lo, hi);
        }
        ((u32x4*)cout)[(size_t)v * 16 + sl] = o;
    }
}

// ---------------- fused Layer: MLP + BN + GRU, 32 rows/wave, reg-pipelined weights ----------------
__global__ __launch_bounds__(256, 2) void k_layer(
    const bf16* __restrict__ cin, bf16* __restrict__ h,
    const bf16* __restrict__ W1, const float* __restrict__ b1,
    const bf16* __restrict__ W2, const float* __restrict__ b2,
    const float* __restrict__ gm, const float* __restrict__ bt,
    const float* __restrict__ mu, const float* __restrict__ vr,
    const bf16* __restrict__ Wih, const bf16* __restrict__ Whh,
    const float* __restrict__ bih, const float* __restrict__ bhh,
    int nT)
{
    __shared__ bf16 lds[4][32][LDP];
    int wid = threadIdx.x >> 6, lane = threadIdx.x & 63;
    int t32 = blockIdx.x * 4 + wid;
    if (t32 >= nT) return;
    int r0 = t32 * 32;
    int rA = lane & 15, u = lane >> 4, ko = u * 8;

    // h row fragments for GRU — issue as early as possible
    bf16x8 ah[2][4];
#pragma unroll
    for (int m = 0; m < 2; ++m){
        const bf16* hp = h + (size_t)(r0 + m*16 + rA) * HD + ko;
#pragma unroll
        for (int kk = 0; kk < 4; ++kk) ah[m][kk] = ldb8(hp + kk * 32);
    }
    // A fragments for GEMM1
    bf16x8 a[2][4];
#pragma unroll
    for (int m = 0; m < 2; ++m){
        const bf16* ap = cin + (size_t)(r0 + m*16 + rA) * HD + ko;
#pragma unroll
        for (int kk = 0; kk < 4; ++kk) a[m][kk] = ldb8(ap + kk * 32);
    }

    auto LW = [&](const bf16* W, bf16x8 (&wb)[4], int t){
        const bf16* p = W + (size_t)(t*16 + rA) * HD + ko;
#pragma unroll
        for (int kk = 0; kk < 4; ++kk) wb[kk] = ldb8(p + kk*32);
    };

    // ---- GEMM1 + ReLU -> LDS (1-ahead W1 prefetch) ----
    {
        bf16x8 wA[4], wB[4];
        auto G1 = [&](bf16x8 (&wb)[4], int t){
            f32x4 c0 = {0,0,0,0}, c1 = {0,0,0,0};
#pragma unroll
            for (int kk = 0; kk < 4; ++kk){
                c0 = MFMA(a[0][kk], wb[kk], c0, 0, 0, 0);
                c1 = MFMA(a[1][kk], wb[kk], c1, 0, 0, 0);
            }
            int c = t*16 + rA;
            float bias = b1[c];
#pragma unroll
            for (int j = 0; j < 4; ++j){
                float v0 = fmaxf(c0[j] + bias, 0.f);
                float v1 = fmaxf(c1[j] + bias, 0.f);
                lds[wid][u*4+j][c]      = (bf16)v0;
                lds[wid][16+u*4+j][c]   = (bf16)v1;
            }
        };
        LW(W1, wA, 0);
#pragma unroll
        for (int tt = 0; tt < 4; ++tt){
            LW(W1, wB, tt*2 + 1);
            G1(wA, tt*2);
            if (tt < 3) LW(W1, wA, tt*2 + 2);
            G1(wB, tt*2 + 1);
        }
    }
    __threadfence_block();

    // ---- GEMM2 + BN -> LDS (1-ahead W2 prefetch) ----
    bf16x8 a2[2][4];
#pragma unroll
    for (int m = 0; m < 2; ++m){
        const bf16* lp = &lds[wid][m*16 + rA][ko];
#pragma unroll
        for (int kk = 0; kk < 4; ++kk) a2[m][kk] = ldb8(lp + kk * 32);
    }
    {
        bf16x8 wA[4], wB[4];
        auto G2 = [&](bf16x8 (&wb)[4], int t){
            f32x4 c0 = {0,0,0,0}, c1 = {0,0,0,0};
#pragma unroll
            for (int kk = 0; kk < 4; ++kk){
                c0 = MFMA(a2[0][kk], wb[kk], c0, 0, 0, 0);
                c1 = MFMA(a2[1][kk], wb[kk], c1, 0, 0, 0);
            }
            int c = t*16 + rA;
            float s = gm[c] * rsqrtf(vr[c] + 1e-5f);
            float o = bt[c] - mu[c] * s;
            float bias = b2[c];
#pragma unroll
            for (int j = 0; j < 4; ++j){
                lds[wid][u*4+j][c]    = (bf16)((c0[j] + bias) * s + o);
                lds[wid][16+u*4+j][c] = (bf16)((c1[j] + bias) * s + o);
            }
        };
        LW(W2, wA, 0);
#pragma unroll
        for (int tt = 0; tt < 4; ++tt){
            LW(W2, wB, tt*2 + 1);
            G2(wA, tt*2);
            if (tt < 3) LW(W2, wA, tt*2 + 2);
            G2(wB, tt*2 + 1);
        }
    }

    // ---- GRU: 3-slot rolling weight prefetch (2 phases ahead) ----
    bf16x8 s0[8], s1[8], s2[8];
    auto LWG = [&](bf16x8 (&s)[8], int t, int g){
        int c = t*16 + rA;
        const bf16* pi = Wih + (size_t)(g*128 + c) * HD + ko;
        const bf16* ph = Whh + (size_t)(g*128 + c) * HD + ko;
#pragma unroll
        for (int kk = 0; kk < 4; ++kk){ s[kk] = ldb8(pi + kk*32); s[4+kk] = ldb8(ph + kk*32); }
    };
    // issue first two phases' loads so they fly during the LDS fence + ac reads
    LWG(s0, 0, 0); LWG(s1, 0, 1);
    __threadfence_block();
    bf16x8 ac[2][4];
#pragma unroll
    for (int m = 0; m < 2; ++m){
        const bf16* lp = &lds[wid][m*16 + rA][ko];
#pragma unroll
        for (int kk = 0; kk < 4; ++kk) ac[m][kk] = ldb8(lp + kk * 32);
    }

    auto MMrz = [&](bf16x8 (&s)[8], f32x4& x0, f32x4& x1){
#pragma unroll
        for (int kk = 0; kk < 4; ++kk){
            x0 = MFMA(ac[0][kk], s[kk],   x0, 0, 0, 0);
            x1 = MFMA(ac[1][kk], s[kk],   x1, 0, 0, 0);
            x0 = MFMA(ah[0][kk], s[4+kk], x0, 0, 0, 0);
            x1 = MFMA(ah[1][kk], s[4+kk], x1, 0, 0, 0);
        }
    };
    auto MMn = [&](bf16x8 (&s)[8], f32x4& p0, f32x4& p1, f32x4& q0, f32x4& q1){
#pragma unroll
        for (int kk = 0; kk < 4; ++kk){
            p0 = MFMA(ac[0][kk], s[kk],   p0, 0, 0, 0);
            p1 = MFMA(ac[1][kk], s[kk],   p1, 0, 0, 0);
            q0 = MFMA(ah[0][kk], s[4+kk], q0, 0, 0, 0);
            q1 = MFMA(ah[1][kk], s[4+kk], q1, 0, 0, 0);
        }
    };

#pragma unroll
    for (int t = 0; t < 8; ++t){
        int c = t*16 + rA;
        // epilogue h values prefetched early (L1-hot from ah row loads)
        float hold[8];
#pragma unroll
        for (int j = 0; j < 4; ++j){
            hold[j]   = (float)h[(size_t)(r0 + u*4 + j) * HD + c];
            hold[4+j] = (float)h[(size_t)(r0 + 16 + u*4 + j) * HD + c];
        }
        LWG(s2, t, 2);
        f32x4 rr0 = {0,0,0,0}, rr1 = {0,0,0,0};
        MMrz(s0, rr0, rr1);
        if (t < 7) LWG(s0, t + 1, 0);
        f32x4 zz0 = {0,0,0,0}, zz1 = {0,0,0,0};
        MMrz(s1, zz0, zz1);
        if (t < 7) LWG(s1, t + 1, 1);
        f32x4 gi0 = {0,0,0,0}, gi1 = {0,0,0,0}, gh0 = {0,0,0,0}, gh1 = {0,0,0,0};
        MMn(s2, gi0, gi1, gh0, gh1);

        float br = bih[c] + bhh[c];
        float bz = bih[c + 128] + bhh[c + 128];
        float bin = bih[c + 256], bhn = bhh[c + 256];
#pragma unroll
        for (int j = 0; j < 4; ++j){
            size_t i0 = (size_t)(r0 + u*4 + j) * HD + c;
            size_t i1 = (size_t)(r0 + 16 + u*4 + j) * HD + c;
            float rg0 = sigm(rr0[j] + br), rg1 = sigm(rr1[j] + br);
            float zg0 = sigm(zz0[j] + bz), zg1 = sigm(zz1[j] + bz);
            float ng0 = tanh_fast(gi0[j] + bin + rg0 * (gh0[j] + bhn));
            float ng1 = tanh_fast(gi1[j] + bin + rg1 * (gh1[j] + bhn));
            h[i0] = (bf16)((1.f - zg0) * ng0 + zg0 * hold[j]);
            h[i1] = (bf16)((1.f - zg1) * ng1 + zg1 * hold[4+j]);
        }
    }
}

// ---------------- final MLP: 128 -> 128 (ReLU) -> 64, f32 out ----------------
__global__ __launch_bounds__(256) void k_final(
    const bf16* __restrict__ hin, const bf16* __restrict__ W1, const float* __restrict__ b1,
    const bf16* __restrict__ W2, const float* __restrict__ b2,
    float* __restrict__ out, int nTiles)
{
    __shared__ bf16 lds[NTPB][16][LDP];
    int wid = threadIdx.x >> 6, lane = threadIdx.x & 63;
    int tile = blockIdx.x * NTPB + wid;
    if (tile >= nTiles) return;
    int r0 = tile * 16;
    int rA = lane & 15, u = lane >> 4, ko = u * 8;

    bf16x8 a[4];
    const bf16* ap = hin + (size_t)(r0 + rA) * HD + ko;
#pragma unroll
    for (int kk = 0; kk < 4; ++kk) a[kk] = ldb8(ap + kk * 32);

#pragma unroll
    for (int t = 0; t < 8; ++t){
        f32x4 acc = {0.f, 0.f, 0.f, 0.f};
        int c = t * 16 + rA;
        const bf16* bp = W1 + (size_t)c * HD + ko;
#pragma unroll
        for (int kk = 0; kk < 4; ++kk)
            acc = MFMA(a[kk], ldb8(bp + kk * 32), acc, 0, 0, 0);
        float bias = b1[c];
#pragma unroll
        for (int j = 0; j < 4; ++j){
            float v = fmaxf(acc[j] + bias, 0.f);
            lds[wid][u * 4 + j][c] = (bf16)v;
        }
    }
    __threadfence_block();
    bf16x8 a2[4];
    const bf16* lp = &lds[wid][rA][ko];
#pragma unroll
    for (int kk = 0; kk < 4; ++kk) a2[kk] = ldb8(lp + kk * 32);

#pragma unroll
    for (int t = 0; t < 4; ++t){
        f32x4 acc = {0.f, 0.f, 0.f, 0.f};
        int c = t * 16 + rA;
        const bf16* bp = W2 + (size_t)c * HD + ko;
#pragma unroll
        for (int kk = 0; kk < 4; ++kk)
            acc = MFMA(a2[kk], ldb8(bp + kk * 32), acc, 0, 0, 0);
        float bias = b2[c];
#pragma unroll
        for (int j = 0; j < 4; ++j)
            out[(size_t)(r0 + u * 4 + j) * 64 + c] = acc[j] + bias;
    }
}

extern "C" void kernel_launch(void* const* d_in, const int* in_sizes, int n_in,
                              void* d_out, int out_size, void* d_ws, size_t ws_size,
                              hipStream_t stream)
{
    const float* x    = (const float*)d_in[0];
    const int*   src  = (const int*)d_in[1];
    const int*   dst  = (const int*)d_in[2];
    const float* lW1  = (const float*)d_in[3];
    const float* lb1  = (const float*)d_in[4];
    const float* lW2  = (const float*)d_in[5];
    const float* lb2  = (const float*)d_in[6];
    const float* gmm  = (const float*)d_in[7];
    const float* bta  = (const float*)d_in[8];
    const float* mun  = (const float*)d_in[9];
    const float* vrr  = (const float*)d_in[10];
    const float* Wih  = (const float*)d_in[11];
    const float* Whh  = (const float*)d_in[12];
    const float* bih  = (const float*)d_in[13];
    const float* bhh  = (const float*)d_in[14];
    const float* fW1  = (const float*)d_in[15];
    const float* fb1  = (const float*)d_in[16];
    const float* fW2  = (const float*)d_in[17];
    const float* fb2  = (const float*)d_in[18];

    int n  = in_sizes[0] / HD;
    int ne = in_sizes[1];
    int E  = ne / 2;                 // dst[E:2E) is sorted
    int L  = in_sizes[3] / (HD * HD);

    char* w = (char*)d_ws;
    auto alloc = [&](size_t bytes) -> char* {
        char* p = w; w += (bytes + 255) & ~(size_t)255; return p;
    };
    bf16* xbf  = (bf16*)alloc((size_t)n * HD * 2);
    bf16* hbf  = (bf16*)alloc((size_t)n * HD * 2);
    bf16* cin  = (bf16*)alloc((size_t)n * HD * 2);
    bf16* W1b  = (bf16*)alloc((size_t)L * HD * HD * 2);
    bf16* W2b  = (bf16*)alloc((size_t)L * HD * HD * 2);
    bf16* Wib  = (bf16*)alloc((size_t)3 * HD * HD * 2);
    bf16* Whb  = (bf16*)alloc((size_t)3 * HD * HD * 2);
    bf16* fW1b = (bf16*)alloc((size_t)HD * HD * 2);
    bf16* fW2b = (bf16*)alloc((size_t)64 * HD * 2);
    int*  degB = (int*)alloc((size_t)n * 4);
    int*  rowsB= (int*)alloc((size_t)(n + 1) * 4);
    int*  rows2= (int*)alloc((size_t)(n + 1) * 4);
    int*  bsum = (int*)alloc(512);
    int*  curB = (int*)alloc((size_t)n * 4);
    int*  colB = (int*)alloc((size_t)E * 4);

    auto cvt = [&](const float* i, bf16* o, int cnt){
        k_cvt<<<(cnt + 255) / 256, 256, 0, stream>>>(i, o, cnt);
    };
    cvt(x,   xbf,  n * HD);
    cvt(lW1, W1b,  L * HD * HD);
    cvt(lW2, W2b,  L * HD * HD);
    cvt(Wih, Wib,  3 * HD * HD);
    cvt(Whh, Whb,  3 * HD * HD);
    cvt(fW1, fW1b, HD * HD);
    cvt(fW2, fW2b, 64 * HD);

    hipMemsetAsync(degB, 0, (size_t)n * 4, stream);
    hipMemsetAsync(hbf, 0, (size_t)n * HD * 2, stream);

    k_bound<<<(n + 1 + 255) / 256, 256, 0, stream>>>(dst + E, E, rows2, n);
    k_count<<<(E + 255) / 256, 256, 0, stream>>>(dst, degB, E);
    int nb = (n + 1023) / 1024;
    k_scan1<<<nb, 256, 0, stream>>>(degB, rowsB, bsum, n);
    k_scan2<<<1, 128, 0, stream>>>(bsum, nb);
    k_scan3<<<(n + 1 + 255) / 256, 256, 0, stream>>>(rowsB, bsum, n, E);
    hipMemcpyAsync(curB, rowsB, (size_t)n * 4, hipMemcpyDeviceToDevice, stream);
    k_fill<<<(E + 255) / 256, 256, 0, stream>>>(src, dst, curB, colB, E);

    int nT32 = (n + 31) / 32;
    int gL = (nT32 + 3) / 4;
    int nT16 = (n + 15) / 16;
    int gF = (nT16 + NTPB - 1) / NTPB;

    const bf16* curp = xbf;
    for (int l = 0; l < L; ++l){
        k_gather<<<(n + 3) / 4, 256, 0, stream>>>(curp, src + E, rows2, colB, rowsB, cin, n);
        k_layer<<<gL, 256, 0, stream>>>(cin, hbf,
            W1b + (size_t)l * HD * HD, lb1 + l * HD,
            W2b + (size_t)l * HD * HD, lb2 + l * HD,
            gmm + l * HD, bta + l * HD, mun + l * HD, vrr + l * HD,
            Wib, Whb, bih, bhh, nT32);
        curp = hbf;
    }
    k_final<<<gF, 256, 0, stream>>>(hbf, fW1b, fb1, fW2b, fb2, (float*)d_out, nT16);
}

// Round 4
// 819.748 us; speedup vs baseline: 1.2528x; 1.2528x over previous
//
#include <hip/hip_runtime.h>
#include <hip/hip_bf16.h>
#include <stdint.h>

typedef __bf16 bf16;
typedef __bf16 bf16x8 __attribute__((ext_vector_type(8)));
typedef float f32x4 __attribute__((ext_vector_type(4)));
typedef uint32_t u32x4 __attribute__((ext_vector_type(4)));

#define HD 128
#define LDP (HD + 8)
#define NTPB 4
#define MFMA __builtin_amdgcn_mfma_f32_16x16x32_bf16

__device__ inline float bflo(uint32_t u){ return __uint_as_float(u << 16); }
__device__ inline float bfhi(uint32_t u){ return __uint_as_float(u & 0xffff0000u); }
__device__ inline uint32_t packbf(float a, float b){
    bf16 x = (bf16)a, y = (bf16)b;
    uint16_t ux = __builtin_bit_cast(uint16_t, x), uy = __builtin_bit_cast(uint16_t, y);
    return (uint32_t)ux | ((uint32_t)uy << 16);
}
__device__ inline bf16x8 ldb8(const bf16* p){ return *(const bf16x8*)p; }
__device__ inline float sigm(float x){ return 1.f / (1.f + __expf(-x)); }
__device__ inline float tanh_fast(float x){ float t = __expf(-2.f * x); return (1.f - t) / (1.f + t); }

// ---------------- weight / activation conversion ----------------
__global__ void k_cvt(const float* __restrict__ in, bf16* __restrict__ out, int n){
    int i = blockIdx.x * 256 + threadIdx.x;
    if (i < n) out[i] = (bf16)in[i];
}

// ---------------- CSR (only the unsorted half needs building) ----------------
__global__ void k_bound(const int* __restrict__ dstB, int E, int* __restrict__ rows2, int n){
    int v = blockIdx.x * 256 + threadIdx.x;
    if (v > n) return;
    int lo = 0, hi = E;
    while (lo < hi){ int mid = (lo + hi) >> 1; if (dstB[mid] < v) lo = mid + 1; else hi = mid; }
    rows2[v] = lo;
}

__global__ void k_count(const int* __restrict__ dst, int* __restrict__ deg, int ne){
    int i = blockIdx.x * 256 + threadIdx.x;
    if (i < ne) atomicAdd(&deg[dst[i]], 1);
}

__global__ void k_scan1(const int* __restrict__ deg, int* __restrict__ rows,
                        int* __restrict__ bsum, int n){
    __shared__ int lds[256];
    int b = blockIdx.x, tid = threadIdx.x;
    int i0 = b * 1024 + tid * 4;
    int v[4]; int s = 0;
#pragma unroll
    for (int j = 0; j < 4; ++j){ int idx = i0 + j; v[j] = (idx < n) ? deg[idx] : 0; s += v[j]; }
    lds[tid] = s; __syncthreads();
    int acc = s;
    for (int off = 1; off < 256; off <<= 1){
        int add = (tid >= off) ? lds[tid - off] : 0;
        __syncthreads();
        acc += add; lds[tid] = acc;
        __syncthreads();
    }
    int run = acc - s;
#pragma unroll
    for (int j = 0; j < 4; ++j){ int idx = i0 + j; if (idx < n) rows[idx] = run; run += v[j]; }
    if (tid == 255) bsum[b] = acc;
}

__global__ void k_scan2(int* __restrict__ bsum, int nb){
    __shared__ int lds[128];
    int tid = threadIdx.x;
    int v = (tid < nb) ? bsum[tid] : 0;
    lds[tid] = v; __syncthreads();
    int acc = v;
    for (int off = 1; off < 128; off <<= 1){
        int add = (tid >= off) ? lds[tid - off] : 0;
        __syncthreads();
        acc += add; lds[tid] = acc;
        __syncthreads();
    }
    if (tid < nb) bsum[tid] = acc - v;
}

__global__ void k_scan3(int* __restrict__ rows, const int* __restrict__ bsum, int n, int total){
    int i = blockIdx.x * 256 + threadIdx.x;
    if (i < n) rows[i] += bsum[i >> 10];
    if (i == n) rows[n] = total;
}

__global__ void k_fill(const int* __restrict__ src, const int* __restrict__ dst,
                       int* __restrict__ cur, int* __restrict__ col, int ne){
    int i = blockIdx.x * 256 + threadIdx.x;
    if (i < ne){ int p = atomicAdd(&cur[dst[i]], 1); col[p] = src[i]; }
}

// ---------------- mean aggregation: 8 neighbors in flight per wave ----------------
__global__ __launch_bounds__(256) void k_gather(
    const bf16* __restrict__ curx,
    const int* __restrict__ srcB, const int* __restrict__ rows2,
    const int* __restrict__ colB, const int* __restrict__ rowsB,
    bf16* __restrict__ cout, int n)
{
    int wid = threadIdx.x >> 6, lane = threadIdx.x & 63;
    int v = blockIdx.x * 4 + wid;
    if (v >= n) return;
    int grp = lane >> 3, sl = lane & 7;    // 8 groups x 8 lanes; lane covers 16B slots sl and sl+8
    int a0 = rows2[v], a1 = rows2[v + 1];
    int b0 = rowsB[v], b1 = rowsB[v + 1];
    int deg = (a1 - a0) + (b1 - b0);
    float inv = (deg > 0) ? 1.f / (float)deg : 0.f;

    const u32x4* base = (const u32x4*)curx;
    float acc[16];
#pragma unroll
    for (int k = 0; k < 16; ++k) acc[k] = 0.f;

    for (int j = a0 + grp; j < a1; j += 8){
        int nb = srcB[j];
        u32x4 q0 = base[(size_t)nb * 16 + sl];
        u32x4 q1 = base[(size_t)nb * 16 + 8 + sl];
#pragma unroll
        for (int k = 0; k < 4; ++k){
            acc[2*k]   += bflo(q0[k]); acc[2*k+1]   += bfhi(q0[k]);
            acc[8+2*k] += bflo(q1[k]); acc[8+2*k+1] += bfhi(q1[k]);
        }
    }
    for (int j = b0 + grp; j < b1; j += 8){
        int nb = colB[j];
        u32x4 q0 = base[(size_t)nb * 16 + sl];
        u32x4 q1 = base[(size_t)nb * 16 + 8 + sl];
#pragma unroll
        for (int k = 0; k < 4; ++k){
            acc[2*k]   += bflo(q0[k]); acc[2*k+1]   += bfhi(q0[k]);
            acc[8+2*k] += bflo(q1[k]); acc[8+2*k+1] += bfhi(q1[k]);
        }
    }
#pragma unroll
    for (int k = 0; k < 16; ++k){
        acc[k] += __shfl_xor(acc[k], 8);
        acc[k] += __shfl_xor(acc[k], 16);
        acc[k] += __shfl_xor(acc[k], 32);
    }
    if (grp == 0){
        u32x4 x0 = base[(size_t)v * 16 + sl];
        u32x4 x1 = base[(size_t)v * 16 + 8 + sl];
        u32x4 o0, o1;
#pragma unroll
        for (int k = 0; k < 4; ++k){
            o0[k] = packbf(bflo(x0[k]) + acc[2*k] * inv,   bfhi(x0[k]) + acc[2*k+1] * inv);
            o1[k] = packbf(bflo(x1[k]) + acc[8+2*k] * inv, bfhi(x1[k]) + acc[8+2*k+1] * inv);
        }
        ((u32x4*)cout)[(size_t)v * 16 + sl]     = o0;
        ((u32x4*)cout)[(size_t)v * 16 + 8 + sl] = o1;
    }
}

// ---------------- fused Layer: cooperative LDS weight staging (global_load_lds) ----------------
// Block = 4 waves = 128 rows. Weight region: 12 x 4KB slots, both-sides XOR swizzle.
// Phases: W1(s0-7) | G1 + stage W2a(s8-11) | G2a + stage W2b(s0-3) | G2b + stage GRUt0(s4-9)
//         | GRU t: stage t+1 into alternating slot set, compute t.
__global__ __launch_bounds__(256, 2) void k_layer(
    const bf16* __restrict__ cin, bf16* __restrict__ h,
    const bf16* __restrict__ W1, const float* __restrict__ b1,
    const bf16* __restrict__ W2, const float* __restrict__ b2,
    const float* __restrict__ gm, const float* __restrict__ bt,
    const float* __restrict__ mu, const float* __restrict__ vr,
    const bf16* __restrict__ Wih, const bf16* __restrict__ Whh,
    const float* __restrict__ bih, const float* __restrict__ bhh)
{
    __shared__ __align__(16) char wsm[49152];       // 12 x 4KB weight slots
    __shared__ __align__(16) bf16 act[4][4096];     // per-wave 8KB activation transpose (swizzled)
    int wid = threadIdx.x >> 6, lane = threadIdx.x & 63;
    int r0 = blockIdx.x * 128 + wid * 32;
    int rA = lane & 15, u = lane >> 4, ko = u * 8;

    auto swz = [](uint32_t off)->uint32_t { return off ^ (((off >> 8) & 7) << 4); };
    auto gload = [&](const char* gsrc, uint32_t ldsoff){
        __builtin_amdgcn_global_load_lds(
            (const __attribute__((address_space(1))) void*)gsrc,
            (__attribute__((address_space(3))) void*)(wsm + ldsoff), 16, 0, 0);
    };
    // stage W1 (32KB -> slots 0..7), 32 chunks of 1KB split across waves
    for (int i = wid; i < 32; i += 4){
        uint32_t off = (uint32_t)i * 1024 + (uint32_t)lane * 16;
        gload((const char*)W1 + swz(off), (uint32_t)i * 1024);
    }

    // A fragments (cin) + h fragments — issue early (HBM latency overlaps staging)
    bf16x8 a[2][4], ah[2][4];
#pragma unroll
    for (int m = 0; m < 2; ++m){
        const bf16* ap = cin + (size_t)(r0 + m*16 + rA) * HD + ko;
        const bf16* hp = h   + (size_t)(r0 + m*16 + rA) * HD + ko;
#pragma unroll
        for (int kk = 0; kk < 4; ++kk){ a[m][kk] = ldb8(ap + kk*32); ah[m][kk] = ldb8(hp + kk*32); }
    }

    auto ldw = [&](int slot, int kk)->bf16x8 {
        uint32_t b = (uint32_t)rA*256 + (uint32_t)u*16 + (uint32_t)kk*64;
        b ^= ((b >> 8) & 7) << 4;
        return *(const bf16x8*)(wsm + slot*4096 + b);
    };
    auto actw = [&](int r, int c, bf16 val){
        uint32_t b = (uint32_t)r*256 + (uint32_t)c*2;
        b ^= ((b >> 8) & 7) << 4;
        *(bf16*)((char*)act[wid] + b) = val;
    };
    auto actr = [&](int r, int kk)->bf16x8 {
        uint32_t b = (uint32_t)r*256 + (uint32_t)(ko + kk*32)*2;
        b ^= ((b >> 8) & 7) << 4;
        return *(const bf16x8*)((char*)act[wid] + b);
    };

    __syncthreads();   // W1 staged

    // ---- GEMM1 + ReLU -> act; stage W2 first half into slots 8..11 ----
    for (int i = wid; i < 16; i += 4){
        uint32_t off = (uint32_t)i * 1024 + (uint32_t)lane * 16;
        gload((const char*)W2 + swz(off), 8*4096u + (uint32_t)i * 1024);
    }
#pragma unroll
    for (int t = 0; t < 8; ++t){
        f32x4 c0 = {0,0,0,0}, c1 = {0,0,0,0};
#pragma unroll
        for (int kk = 0; kk < 4; ++kk){
            bf16x8 wb = ldw(t, kk);
            c0 = MFMA(a[0][kk], wb, c0, 0, 0, 0);
            c1 = MFMA(a[1][kk], wb, c1, 0, 0, 0);
        }
        int c = t*16 + rA;
        float bias = b1[c];
#pragma unroll
        for (int j = 0; j < 4; ++j){
            actw(u*4 + j,      c, (bf16)fmaxf(c0[j] + bias, 0.f));
            actw(16 + u*4 + j, c, (bf16)fmaxf(c1[j] + bias, 0.f));
        }
    }
    __syncthreads();   // W2a staged; slots 0-7 free

    // ---- GEMM2 + BN -> act; stage W2 second half into slots 0..3 ----
    for (int i = wid; i < 16; i += 4){
        uint32_t off = 16384u + (uint32_t)i * 1024 + (uint32_t)lane * 16;
        gload((const char*)W2 + swz(off), (uint32_t)i * 1024);
    }
    bf16x8 a2[2][4];
#pragma unroll
    for (int m = 0; m < 2; ++m)
#pragma unroll
        for (int kk = 0; kk < 4; ++kk) a2[m][kk] = actr(m*16 + rA, kk);

    auto g2step = [&](int t, int slot){
        f32x4 c0 = {0,0,0,0}, c1 = {0,0,0,0};
#pragma unroll
        for (int kk = 0; kk < 4; ++kk){
            bf16x8 wb = ldw(slot, kk);
            c0 = MFMA(a2[0][kk], wb, c0, 0, 0, 0);
            c1 = MFMA(a2[1][kk], wb, c1, 0, 0, 0);
        }
        int c = t*16 + rA;
        float s = gm[c] * rsqrtf(vr[c] + 1e-5f);
        float o = bt[c] - mu[c] * s;
        float bias = b2[c];
#pragma unroll
        for (int j = 0; j < 4; ++j){
            actw(u*4 + j,      c, (bf16)((c0[j] + bias) * s + o));
            actw(16 + u*4 + j, c, (bf16)((c1[j] + bias) * s + o));
        }
    };
#pragma unroll
    for (int t = 0; t < 4; ++t) g2step(t, 8 + t);
    __syncthreads();   // W2b staged; slots 4-11 free

    auto stageGRU = [&](int t){
        uint32_t sb = (t & 1) ? 10u : 4u;
        for (int i = wid; i < 24; i += 4){
            int p = i >> 2, s = i & 3;
            int g = p >> 1, m = p & 1;
            const char* Wsrc = (const char*)(m ? Whh : Wih) + (size_t)g*32768 + (size_t)t*4096;
            uint32_t slot = sb + (uint32_t)p; if (slot >= 12) slot -= 12;
            uint32_t off = (uint32_t)s * 1024 + (uint32_t)lane * 16;
            gload(Wsrc + swz(off), slot*4096 + (uint32_t)s * 1024);
        }
    };
    stageGRU(0);                                  // -> slots 4..9
#pragma unroll
    for (int t = 4; t < 8; ++t) g2step(t, t - 4); // GEMM2 second half from slots 0..3
    __syncthreads();   // GRU t0 staged

    // ---- GRU: double-buffered t-loop ----
    bf16x8 ac[2][4];
#pragma unroll
    for (int m = 0; m < 2; ++m)
#pragma unroll
        for (int kk = 0; kk < 4; ++kk) ac[m][kk] = actr(m*16 + rA, kk);

#pragma unroll
    for (int t = 0; t < 8; ++t){
        if (t < 7) stageGRU(t + 1);
        uint32_t sb = (t & 1) ? 10u : 4u;
        int s0 = sb, s1 = sb+1, s2 = sb+2, s3 = sb+3, s4 = sb+4, s5 = sb+5;
        if (s2 >= 12) s2 -= 12; if (s3 >= 12) s3 -= 12;
        if (s4 >= 12) s4 -= 12; if (s5 >= 12) s5 -= 12;
        if (s1 >= 12) s1 -= 12;
        int c = t*16 + rA;
        float hold[8];
#pragma unroll
        for (int j = 0; j < 4; ++j){
            hold[j]   = (float)h[(size_t)(r0 + u*4 + j) * HD + c];
            hold[4+j] = (float)h[(size_t)(r0 + 16 + u*4 + j) * HD + c];
        }
        f32x4 rr0={0,0,0,0}, rr1={0,0,0,0}, zz0={0,0,0,0}, zz1={0,0,0,0};
        f32x4 gi0={0,0,0,0}, gi1={0,0,0,0}, gh0={0,0,0,0}, gh1={0,0,0,0};
#pragma unroll
        for (int kk = 0; kk < 4; ++kk){
            bf16x8 Bri = ldw(s0, kk), Brh = ldw(s1, kk);
            bf16x8 Bzi = ldw(s2, kk), Bzh = ldw(s3, kk);
            bf16x8 Bni = ldw(s4, kk), Bnh = ldw(s5, kk);
            rr0 = MFMA(ac[0][kk], Bri, rr0, 0, 0, 0);
            rr1 = MFMA(ac[1][kk], Bri, rr1, 0, 0, 0);
            rr0 = MFMA(ah[0][kk], Brh, rr0, 0, 0, 0);
            rr1 = MFMA(ah[1][kk], Brh, rr1, 0, 0, 0);
            zz0 = MFMA(ac[0][kk], Bzi, zz0, 0, 0, 0);
            zz1 = MFMA(ac[1][kk], Bzi, zz1, 0, 0, 0);
            zz0 = MFMA(ah[0][kk], Bzh, zz0, 0, 0, 0);
            zz1 = MFMA(ah[1][kk], Bzh, zz1, 0, 0, 0);
            gi0 = MFMA(ac[0][kk], Bni, gi0, 0, 0, 0);
            gi1 = MFMA(ac[1][kk], Bni, gi1, 0, 0, 0);
            gh0 = MFMA(ah[0][kk], Bnh, gh0, 0, 0, 0);
            gh1 = MFMA(ah[1][kk], Bnh, gh1, 0, 0, 0);
        }
        float br = bih[c] + bhh[c];
        float bz = bih[c + 128] + bhh[c + 128];
        float bin = bih[c + 256], bhn = bhh[c + 256];
#pragma unroll
        for (int j = 0; j < 4; ++j){
            size_t i0 = (size_t)(r0 + u*4 + j) * HD + c;
            size_t i1 = (size_t)(r0 + 16 + u*4 + j) * HD + c;
            float rg0 = sigm(rr0[j] + br), rg1 = sigm(rr1[j] + br);
            float zg0 = sigm(zz0[j] + bz), zg1 = sigm(zz1[j] + bz);
            float ng0 = tanh_fast(gi0[j] + bin + rg0 * (gh0[j] + bhn));
            float ng1 = tanh_fast(gi1[j] + bin + rg1 * (gh1[j] + bhn));
            h[i0] = (bf16)((1.f - zg0) * ng0 + zg0 * hold[j]);
            h[i1] = (bf16)((1.f - zg1) * ng1 + zg1 * hold[4+j]);
        }
        __syncthreads();
    }
}

// ---------------- final MLP: 128 -> 128 (ReLU) -> 64, f32 out ----------------
__global__ __launch_bounds__(256) void k_final(
    const bf16* __restrict__ hin, const bf16* __restrict__ W1, const float* __restrict__ b1,
    const bf16* __restrict__ W2, const float* __restrict__ b2,
    float* __restrict__ out, int nTiles)
{
    __shared__ bf16 lds[NTPB][16][LDP];
    int wid = threadIdx.x >> 6, lane = threadIdx.x & 63;
    int tile = blockIdx.x * NTPB + wid;
    if (tile >= nTiles) return;
    int r0 = tile * 16;
    int rA = lane & 15, u = lane >> 4, ko = u * 8;

    bf16x8 a[4];
    const bf16* ap = hin + (size_t)(r0 + rA) * HD + ko;
#pragma unroll
    for (int kk = 0; kk < 4; ++kk) a[kk] = ldb8(ap + kk * 32);

#pragma unroll
    for (int t = 0; t < 8; ++t){
        f32x4 acc = {0.f, 0.f, 0.f, 0.f};
        int c = t * 16 + rA;
        const bf16* bp = W1 + (size_t)c * HD + ko;
#pragma unroll
        for (int kk = 0; kk < 4; ++kk)
            acc = MFMA(a[kk], ldb8(bp + kk * 32), acc, 0, 0, 0);
        float bias = b1[c];
#pragma unroll
        for (int j = 0; j < 4; ++j){
            float v = fmaxf(acc[j] + bias, 0.f);
            lds[wid][u * 4 + j][c] = (bf16)v;
        }
    }
    __threadfence_block();
    bf16x8 a2[4];
    const bf16* lp = &lds[wid][rA][ko];
#pragma unroll
    for (int kk = 0; kk < 4; ++kk) a2[kk] = ldb8(lp + kk * 32);

#pragma unroll
    for (int t = 0; t < 4; ++t){
        f32x4 acc = {0.f, 0.f, 0.f, 0.f};
        int c = t * 16 + rA;
        const bf16* bp = W2 + (size_t)c * HD + ko;
#pragma unroll
        for (int kk = 0; kk < 4; ++kk)
            acc = MFMA(a2[kk], ldb8(bp + kk * 32), acc, 0, 0, 0);
        float bias = b2[c];
#pragma unroll
        for (int j = 0; j < 4; ++j)
            out[(size_t)(r0 + u * 4 + j) * 64 + c] = acc[j] + bias;
    }
}

extern "C" void kernel_launch(void* const* d_in, const int* in_sizes, int n_in,
                              void* d_out, int out_size, void* d_ws, size_t ws_size,
                              hipStream_t stream)
{
    const float* x    = (const float*)d_in[0];
    const int*   src  = (const int*)d_in[1];
    const int*   dst  = (const int*)d_in[2];
    const float* lW1  = (const float*)d_in[3];
    const float* lb1  = (const float*)d_in[4];
    const float* lW2  = (const float*)d_in[5];
    const float* lb2  = (const float*)d_in[6];
    const float* gmm  = (const float*)d_in[7];
    const float* bta  = (const float*)d_in[8];
    const float* mun  = (const float*)d_in[9];
    const float* vrr  = (const float*)d_in[10];
    const float* Wih  = (const float*)d_in[11];
    const float* Whh  = (const float*)d_in[12];
    const float* bih  = (const float*)d_in[13];
    const float* bhh  = (const float*)d_in[14];
    const float* fW1  = (const float*)d_in[15];
    const float* fb1  = (const float*)d_in[16];
    const float* fW2  = (const float*)d_in[17];
    const float* fb2  = (const float*)d_in[18];

    int n  = in_sizes[0] / HD;
    int ne = in_sizes[1];
    int E  = ne / 2;                    // dst[E:2E) is sorted
    int L  = in_sizes[3] / (HD * HD);
    int nPad = (n + 127) & ~127;        // row-padded so k_layer needs no bounds checks

    char* w = (char*)d_ws;
    auto alloc = [&](size_t bytes) -> char* {
        char* p = w; w += (bytes + 255) & ~(size_t)255; return p;
    };
    bf16* xbf  = (bf16*)alloc((size_t)nPad * HD * 2);
    bf16* hbf  = (bf16*)alloc((size_t)nPad * HD * 2);
    bf16* cin  = (bf16*)alloc((size_t)nPad * HD * 2);
    bf16* W1b  = (bf16*)alloc((size_t)L * HD * HD * 2);
    bf16* W2b  = (bf16*)alloc((size_t)L * HD * HD * 2);
    bf16* Wib  = (bf16*)alloc((size_t)3 * HD * HD * 2);
    bf16* Whb  = (bf16*)alloc((size_t)3 * HD * HD * 2);
    bf16* fW1b = (bf16*)alloc((size_t)HD * HD * 2);
    bf16* fW2b = (bf16*)alloc((size_t)64 * HD * 2);
    int*  degB = (int*)alloc((size_t)n * 4);
    int*  rowsB= (int*)alloc((size_t)(n + 1) * 4);
    int*  rows2= (int*)alloc((size_t)(n + 1) * 4);
    int*  bsum = (int*)alloc(512);
    int*  curB = (int*)alloc((size_t)n * 4);
    int*  colB = (int*)alloc((size_t)E * 4);

    auto cvt = [&](const float* i, bf16* o, int cnt){
        k_cvt<<<(cnt + 255) / 256, 256, 0, stream>>>(i, o, cnt);
    };
    cvt(x,   xbf,  n * HD);
    cvt(lW1, W1b,  L * HD * HD);
    cvt(lW2, W2b,  L * HD * HD);
    cvt(Wih, Wib,  3 * HD * HD);
    cvt(Whh, Whb,  3 * HD * HD);
    cvt(fW1, fW1b, HD * HD);
    cvt(fW2, fW2b, 64 * HD);

    hipMemsetAsync(degB, 0, (size_t)n * 4, stream);
    hipMemsetAsync(hbf, 0, (size_t)nPad * HD * 2, stream);

    k_bound<<<(n + 1 + 255) / 256, 256, 0, stream>>>(dst + E, E, rows2, n);
    k_count<<<(E + 255) / 256, 256, 0, stream>>>(dst, degB, E);
    int nb = (n + 1023) / 1024;
    k_scan1<<<nb, 256, 0, stream>>>(degB, rowsB, bsum, n);
    k_scan2<<<1, 128, 0, stream>>>(bsum, nb);
    k_scan3<<<(n + 1 + 255) / 256, 256, 0, stream>>>(rowsB, bsum, n, E);
    hipMemcpyAsync(curB, rowsB, (size_t)n * 4, hipMemcpyDeviceToDevice, stream);
    k_fill<<<(E + 255) / 256, 256, 0, stream>>>(src, dst, curB, colB, E);

    int gL = nPad / 128;
    int nT16 = (n + 15) / 16;
    int gF = (nT16 + NTPB - 1) / NTPB;

    const bf16* curp = xbf;
    for (int l = 0; l < L; ++l){
        k_gather<<<(n + 3) / 4, 256, 0, stream>>>(curp, src + E, rows2, colB, rowsB, cin, n);
        k_layer<<<gL, 256, 0, stream>>>(cin, hbf,
            W1b + (size_t)l * HD * HD, lb1 + l * HD,
            W2b + (size_t)l * HD * HD, lb2 + l * HD,
            gmm + l * HD, bta + l * HD, mun + l * HD, vrr + l * HD,
            Wib, Whb, bih, bhh);
        curp = hbf;
    }
    k_final<<<gF, 256, 0, stream>>>(hbf, fW1b, fb1, fW2b, fb2, (float*)d_out, nT16);
}